// Round 2
// 251.255 us; speedup vs baseline: 1.0441x; 1.0441x over previous
//
#include <hip/hip_runtime.h>
#include <math.h>
#include <stdint.h>

// Problem constants (B=16, I=256, T=8192), x float32, out float32
#define T_LEN 8192
#define NSTEP 8189   // T-3 sampled steps
#define NB 16
#define NI 256
#define OUTT 8190    // T-2 output time length
#define CHUNK 128
#define NCHUNK 64    // 64*128 = 8192 >= NSTEP

// native vector types for nontemporal builtins (HIP_vector_type not accepted)
typedef float f32x4 __attribute__((ext_vector_type(4)));
typedef float f32x2 __attribute__((ext_vector_type(2)));

// ---------------- threefry2x32 (JAX-compatible, 20 rounds) ----------------
__device__ __forceinline__ uint32_t rotl32(uint32_t v, int r) {
  return (v << r) | (v >> (32 - r));
}

__device__ __forceinline__ void tf2x32(uint32_t k0, uint32_t k1,
                                       uint32_t x0, uint32_t x1,
                                       uint32_t& o0, uint32_t& o1) {
  uint32_t k2 = k0 ^ k1 ^ 0x1BD11BDAu;
  x0 += k0; x1 += k1;
  // group 1 (rot set A: 13,15,26,6)
  x0 += x1; x1 = rotl32(x1, 13); x1 ^= x0;
  x0 += x1; x1 = rotl32(x1, 15); x1 ^= x0;
  x0 += x1; x1 = rotl32(x1, 26); x1 ^= x0;
  x0 += x1; x1 = rotl32(x1,  6); x1 ^= x0;
  x0 += k1; x1 += k2 + 1u;
  // group 2 (rot set B: 17,29,16,24)
  x0 += x1; x1 = rotl32(x1, 17); x1 ^= x0;
  x0 += x1; x1 = rotl32(x1, 29); x1 ^= x0;
  x0 += x1; x1 = rotl32(x1, 16); x1 ^= x0;
  x0 += x1; x1 = rotl32(x1, 24); x1 ^= x0;
  x0 += k2; x1 += k0 + 2u;
  // group 3 (A)
  x0 += x1; x1 = rotl32(x1, 13); x1 ^= x0;
  x0 += x1; x1 = rotl32(x1, 15); x1 ^= x0;
  x0 += x1; x1 = rotl32(x1, 26); x1 ^= x0;
  x0 += x1; x1 = rotl32(x1,  6); x1 ^= x0;
  x0 += k0; x1 += k1 + 3u;
  // group 4 (B)
  x0 += x1; x1 = rotl32(x1, 17); x1 ^= x0;
  x0 += x1; x1 = rotl32(x1, 29); x1 ^= x0;
  x0 += x1; x1 = rotl32(x1, 16); x1 ^= x0;
  x0 += x1; x1 = rotl32(x1, 24); x1 ^= x0;
  x0 += k1; x1 += k2 + 4u;
  // group 5 (A)
  x0 += x1; x1 = rotl32(x1, 13); x1 ^= x0;
  x0 += x1; x1 = rotl32(x1, 15); x1 ^= x0;
  x0 += x1; x1 = rotl32(x1, 26); x1 ^= x0;
  x0 += x1; x1 = rotl32(x1,  6); x1 ^= x0;
  x0 += k2; x1 += k0 + 5u;
  o0 = x0; o1 = x1;
}

// Correctly-rounded float32 log via double precision (validated bit-exact vs ref)
__device__ __forceinline__ float f32log_cr(float x) {
  return (float)log((double)x);
}

// jax uniform(minval=tiny,maxval=1) -> gumbel, exact f32 semantics (validated)
__device__ __forceinline__ float bits_to_gumbel(uint32_t bits) {
  uint32_t fb = (bits >> 9) | 0x3F800000u;
  float u = __uint_as_float(fb) - 1.0f;           // exact, in [0, 1)
  if (u == 0.0f) u = 1.17549435e-38f;             // finfo(f32).tiny
  float inner = f32log_cr(u);                     // < 0
  float outer = f32log_cr(-inner);
  return -outer;
}

__device__ __forceinline__ int chain_step(int sigma, uint32_t dv) {
  int s = (sigma == 5) ? (int)(dv >> 2) : (int)(dv & 3u);
  return (sigma % 3) * 3 + s;
}

// -------- Kernel 1 (fused): decision bytes + per-chunk 9-state maps --------
// Decision math byte-identical to the validated round-2/3 kernel.
__global__ void k_dec_spec(const int* __restrict__ seedp,
                           uint8_t* __restrict__ dec,
                           uint8_t* __restrict__ Mend) {
  __shared__ uint8_t ld[CHUNK];
  int c = blockIdx.x, b = blockIdx.y;
  int t = c * CHUNK + threadIdx.x;

  if (t < NSTEP) {
    uint32_t sk0 = 0u;                      // threefry_seed(int32): hi word 0
    uint32_t sk1 = (uint32_t)seedp[0];
    uint32_t kt0, kt1;
    tf2x32(sk0, sk1, 0u, (uint32_t)t, kt0, kt1);  // split key for step t

    float g[3];
#pragma unroll
    for (int e = 0; e < 3; ++e) {
      uint32_t o0, o1;
      tf2x32(kt0, kt1, 0u, (uint32_t)(3 * b + e), o0, o1);
      g[e] = bits_to_gumbel(o0 ^ o1);
    }

    const double pd = 0.1;
    const double sd = 1.0 - 2.0 * 0.1;
    const float Lp  = f32log_cr((float)pd);
    const float Ls  = f32log_cr((float)sd);
    const float Lb1 = f32log_cr((float)(sd / (pd + sd)));
    const float Lb2 = f32log_cr((float)(pd / (pd + sd)));

    float z0 = g[0] + Lp, z1 = g[1] + Ls, z2 = g[2] + Lp;
    int an = 0; float best = z0;
    if (z1 > best) { best = z1; an = 1; }
    if (z2 > best) { an = 2; }
    int as_ = ((g[2] + Lb2) > (g[1] + Lb1)) ? 2 : 1;

    uint8_t v = (uint8_t)(an | (as_ << 2));
    ld[threadIdx.x] = v;
    dec[b * T_LEN + t] = v;
  }
  __syncthreads();

  if (threadIdx.x < 9) {
    int sigma = threadIdx.x;
    int n = min(CHUNK, NSTEP - c * CHUNK);
    for (int k = 0; k < n; ++k) sigma = chain_step(sigma, ld[k]);
    Mend[(b * NCHUNK + c) * 9 + threadIdx.x] = (uint8_t)sigma;
  }
}

// -------- Kernel 2 (fused): fold chunk maps + apply -> st2 -----------------
// One block per batch, 64 threads (one per chunk). Apply loop reads dec as
// uint32 words (unrolled -> loads hoisted, no per-byte load latency chain).
__global__ void k_chain(const uint8_t* __restrict__ dec,
                        const uint8_t* __restrict__ Mend,
                        uint8_t* __restrict__ st2) {
  __shared__ uint8_t m[NCHUNK * 9];
  __shared__ uint8_t entry[NCHUNK];
  int b = blockIdx.x;
  for (int idx = threadIdx.x; idx < NCHUNK * 9; idx += blockDim.x)
    m[idx] = Mend[b * NCHUNK * 9 + idx];
  __syncthreads();
  if (threadIdx.x == 0) {
    int sigma = 4;  // (prev2,prev1) = (1,1)
    for (int cc = 0; cc < NCHUNK; ++cc) {
      entry[cc] = (uint8_t)sigma;
      sigma = m[cc * 9 + sigma];
    }
  }
  __syncthreads();
  int c = threadIdx.x;
  int t0 = c * CHUNK;
  int sigma = entry[c];
  const uint32_t* dw = (const uint32_t*)(dec + b * T_LEN + t0);  // 4-aligned
  uint8_t* s2 = st2 + b * T_LEN;
  if (c == 0) s2[0] = 1;  // st[1] = 1 -> st2[0]
#pragma unroll 8
  for (int wi = 0; wi < CHUNK / 4; ++wi) {
    uint32_t word = dw[wi];
#pragma unroll
    for (int r = 0; r < 4; ++r) {
      int t = t0 + 4 * wi + r;
      uint32_t dv = (word >> (8 * r)) & 0xFFu;
      int s = (sigma == 5) ? (int)(dv >> 2) : (int)(dv & 3u);
      if (t < NSTEP) s2[t + 1] = (uint8_t)s;  // guard: don't stomp next batch's st2[0]
      sigma = (sigma % 3) * 3 + s;
    }
  }
}

// -------- Kernel 3: lane-contiguous register-window gather -----------------
// Each thread produces 4 consecutive outputs out[J+sig .. J+sig+3] with
// J = 4*k (lane pitch 16B -> every float4 load/store instruction is one
// contiguous 1KB wave segment, ~16 cache lines instead of 64).
// sig in {0,2} is the per-row parity shift: out row stride 8190 floats means
// odd rows start 8B-misaligned; shifting the tile by 2 makes all main-path
// float4 stores 16B-aligned. The window x[J+sig .. J+sig+5] comes from two
// aligned float4 loads at J and J+4; the second one lands on lines the
// neighboring lane just fetched (L1 hit), so no extra HBM traffic.
// One spare thread per row (k==2047) handles the 2-float head (odd rows) /
// tail (even rows). Non-temporal stores keep x resident in the 256MB L3.
__global__ void k_gather(const float* __restrict__ x,
                         const uint8_t* __restrict__ st2,
                         float* __restrict__ out) {
  int i = blockIdx.y, b = blockIdx.z;
  int row = b * NI + i;
  int sig = (row & 1) ? 2 : 0;   // row*8190 mod 4 = 2*(row&1)
  int k = blockIdx.x * blockDim.x + threadIdx.x;   // 0..2047
  const float* xr = x + (size_t)row * (size_t)T_LEN;
  float* orow = out + (size_t)row * (size_t)OUTT;
  const uint8_t* sp = st2 + b * T_LEN;

  if (k < 2047) {
    int J = 4 * k;                                  // 0..8184, multiple of 4
    float4 A  = *(const float4*)(xr + J);           // x[J..J+3]
    float4 Bv = *(const float4*)(xr + J + 4);       // x[J+4..J+7]
    uint32_t s0 = *(const uint32_t*)(sp + J);       // st2[J..J+3]
    uint32_t s1 = *(const uint32_t*)(sp + J + 4);   // st2[J+4..J+7]
    float w[8] = {A.x, A.y, A.z, A.w, Bv.x, Bv.y, Bv.z, Bv.w};

    float res[4];
    if (sig == 0) {
      uint32_t sb[4] = { s0 & 0xFFu, (s0 >> 8) & 0xFFu,
                         (s0 >> 16) & 0xFFu, s0 >> 24 };
#pragma unroll
      for (int m = 0; m < 4; ++m) {
        uint32_t s = sb[m];
        res[m] = (s == 0) ? w[m] : ((s == 1) ? w[m + 1] : w[m + 2]);
      }
    } else {
      uint32_t sb[4] = { (s0 >> 16) & 0xFFu, s0 >> 24,
                         s1 & 0xFFu, (s1 >> 8) & 0xFFu };
#pragma unroll
      for (int m = 0; m < 4; ++m) {
        uint32_t s = sb[m];
        res[m] = (s == 0) ? w[m + 2] : ((s == 1) ? w[m + 3] : w[m + 4]);
      }
    }
    f32x4 r = { res[0], res[1], res[2], res[3] };
    __builtin_nontemporal_store(r, (f32x4*)(orow + J + sig));
  } else {
    if (sig == 0) {
      // tail: out j = 8188, 8189
      float4 A = *(const float4*)(xr + 8188);       // x[8188..8191]
      uint32_t s0 = *(const uint32_t*)(sp + 8188);
      uint32_t b0 = s0 & 0xFFu, b1 = (s0 >> 8) & 0xFFu;
      float w0 = A.x, w1 = A.y, w2 = A.z, w3 = A.w;
      float r0 = (b0 == 0) ? w0 : ((b0 == 1) ? w1 : w2);
      float r1 = (b1 == 0) ? w1 : ((b1 == 1) ? w2 : w3);
      f32x2 r = { r0, r1 };
      __builtin_nontemporal_store(r, (f32x2*)(orow + 8188));
    } else {
      // head: out j = 0, 1
      float4 A = *(const float4*)(xr);              // x[0..3]
      uint32_t s0 = *(const uint32_t*)(sp);
      uint32_t b0 = s0 & 0xFFu, b1 = (s0 >> 8) & 0xFFu;
      float w0 = A.x, w1 = A.y, w2 = A.z, w3 = A.w;
      float r0 = (b0 == 0) ? w0 : ((b0 == 1) ? w1 : w2);
      float r1 = (b1 == 0) ? w1 : ((b1 == 1) ? w2 : w3);
      f32x2 r = { r0, r1 };
      __builtin_nontemporal_store(r, (f32x2*)(orow));
    }
  }
}

extern "C" void kernel_launch(void* const* d_in, const int* in_sizes, int n_in,
                              void* d_out, int out_size, void* d_ws, size_t ws_size,
                              hipStream_t stream) {
  const float* x   = (const float*)d_in[0];   // float32 input
  const int* seedp = (const int*)d_in[1];
  float* out       = (float*)d_out;           // float32 output

  uint8_t* ws    = (uint8_t*)d_ws;
  uint8_t* dec   = ws;                        // 16*8192 = 131072 B
  uint8_t* st2   = dec + NB * T_LEN;          // 131072 B
  uint8_t* Mend  = st2 + NB * T_LEN;          // 16*64*9 = 9216 B

  k_dec_spec<<<dim3(NCHUNK, NB), CHUNK, 0, stream>>>(seedp, dec, Mend);
  k_chain<<<NB, NCHUNK, 0, stream>>>(dec, Mend, st2);
  // 2048 threads per row (2047 main + 1 head/tail), 8 blocks of 256 per row
  k_gather<<<dim3(8, NI, NB), 256, 0, stream>>>(x, st2, out);
}

// Round 3
// 251.076 us; speedup vs baseline: 1.0448x; 1.0007x over previous
//
#include <hip/hip_runtime.h>
#include <math.h>
#include <stdint.h>

// Problem constants (B=16, I=256, T=8192), x float32, out float32
#define T_LEN 8192
#define NSTEP 8189   // T-3 sampled steps
#define NB 16
#define NI 256
#define OUTT 8190    // T-2 output time length
#define CHUNK 128
#define NCHUNK 64    // 64*128 = 8192 >= NSTEP

// native vector types for nontemporal builtins (HIP_vector_type not accepted)
typedef float f32x4 __attribute__((ext_vector_type(4)));

// ---------------- threefry2x32 (JAX-compatible, 20 rounds) ----------------
__device__ __forceinline__ uint32_t rotl32(uint32_t v, int r) {
  return (v << r) | (v >> (32 - r));
}

__device__ __forceinline__ void tf2x32(uint32_t k0, uint32_t k1,
                                       uint32_t x0, uint32_t x1,
                                       uint32_t& o0, uint32_t& o1) {
  uint32_t k2 = k0 ^ k1 ^ 0x1BD11BDAu;
  x0 += k0; x1 += k1;
  // group 1 (rot set A: 13,15,26,6)
  x0 += x1; x1 = rotl32(x1, 13); x1 ^= x0;
  x0 += x1; x1 = rotl32(x1, 15); x1 ^= x0;
  x0 += x1; x1 = rotl32(x1, 26); x1 ^= x0;
  x0 += x1; x1 = rotl32(x1,  6); x1 ^= x0;
  x0 += k1; x1 += k2 + 1u;
  // group 2 (rot set B: 17,29,16,24)
  x0 += x1; x1 = rotl32(x1, 17); x1 ^= x0;
  x0 += x1; x1 = rotl32(x1, 29); x1 ^= x0;
  x0 += x1; x1 = rotl32(x1, 16); x1 ^= x0;
  x0 += x1; x1 = rotl32(x1, 24); x1 ^= x0;
  x0 += k2; x1 += k0 + 2u;
  // group 3 (A)
  x0 += x1; x1 = rotl32(x1, 13); x1 ^= x0;
  x0 += x1; x1 = rotl32(x1, 15); x1 ^= x0;
  x0 += x1; x1 = rotl32(x1, 26); x1 ^= x0;
  x0 += x1; x1 = rotl32(x1,  6); x1 ^= x0;
  x0 += k0; x1 += k1 + 3u;
  // group 4 (B)
  x0 += x1; x1 = rotl32(x1, 17); x1 ^= x0;
  x0 += x1; x1 = rotl32(x1, 29); x1 ^= x0;
  x0 += x1; x1 = rotl32(x1, 16); x1 ^= x0;
  x0 += x1; x1 = rotl32(x1, 24); x1 ^= x0;
  x0 += k1; x1 += k2 + 4u;
  // group 5 (A)
  x0 += x1; x1 = rotl32(x1, 13); x1 ^= x0;
  x0 += x1; x1 = rotl32(x1, 15); x1 ^= x0;
  x0 += x1; x1 = rotl32(x1, 26); x1 ^= x0;
  x0 += x1; x1 = rotl32(x1,  6); x1 ^= x0;
  x0 += k2; x1 += k0 + 5u;
  o0 = x0; o1 = x1;
}

// Correctly-rounded float32 log via double precision (validated bit-exact vs ref)
__device__ __forceinline__ float f32log_cr(float x) {
  return (float)log((double)x);
}

// jax uniform(minval=tiny,maxval=1) -> gumbel, exact f32 semantics (validated)
__device__ __forceinline__ float bits_to_gumbel(uint32_t bits) {
  uint32_t fb = (bits >> 9) | 0x3F800000u;
  float u = __uint_as_float(fb) - 1.0f;           // exact, in [0, 1)
  if (u == 0.0f) u = 1.17549435e-38f;             // finfo(f32).tiny
  float inner = f32log_cr(u);                     // < 0
  float outer = f32log_cr(-inner);
  return -outer;
}

__device__ __forceinline__ int chain_step(int sigma, uint32_t dv) {
  int s = (sigma == 5) ? (int)(dv >> 2) : (int)(dv & 3u);
  return (sigma % 3) * 3 + s;
}

// -------- Kernel 1 (fused): decision bytes + per-chunk 9-state maps --------
// Decision math byte-identical to the validated round-2/3 kernel.
__global__ void k_dec_spec(const int* __restrict__ seedp,
                           uint8_t* __restrict__ dec,
                           uint8_t* __restrict__ Mend) {
  __shared__ uint8_t ld[CHUNK];
  int c = blockIdx.x, b = blockIdx.y;
  int t = c * CHUNK + threadIdx.x;

  if (t < NSTEP) {
    uint32_t sk0 = 0u;                      // threefry_seed(int32): hi word 0
    uint32_t sk1 = (uint32_t)seedp[0];
    uint32_t kt0, kt1;
    tf2x32(sk0, sk1, 0u, (uint32_t)t, kt0, kt1);  // split key for step t

    float g[3];
#pragma unroll
    for (int e = 0; e < 3; ++e) {
      uint32_t o0, o1;
      tf2x32(kt0, kt1, 0u, (uint32_t)(3 * b + e), o0, o1);
      g[e] = bits_to_gumbel(o0 ^ o1);
    }

    const double pd = 0.1;
    const double sd = 1.0 - 2.0 * 0.1;
    const float Lp  = f32log_cr((float)pd);
    const float Ls  = f32log_cr((float)sd);
    const float Lb1 = f32log_cr((float)(sd / (pd + sd)));
    const float Lb2 = f32log_cr((float)(pd / (pd + sd)));

    float z0 = g[0] + Lp, z1 = g[1] + Ls, z2 = g[2] + Lp;
    int an = 0; float best = z0;
    if (z1 > best) { best = z1; an = 1; }
    if (z2 > best) { an = 2; }
    int as_ = ((g[2] + Lb2) > (g[1] + Lb1)) ? 2 : 1;

    uint8_t v = (uint8_t)(an | (as_ << 2));
    ld[threadIdx.x] = v;
    dec[b * T_LEN + t] = v;
  }
  __syncthreads();

  if (threadIdx.x < 9) {
    int sigma = threadIdx.x;
    int n = min(CHUNK, NSTEP - c * CHUNK);
    for (int k = 0; k < n; ++k) sigma = chain_step(sigma, ld[k]);
    Mend[(b * NCHUNK + c) * 9 + threadIdx.x] = (uint8_t)sigma;
  }
}

// -------- Kernel 2 (fused): fold chunk maps + apply -> st2 -----------------
// One block per batch, 64 threads (one per chunk). Apply loop reads dec as
// uint32 words (unrolled -> loads hoisted, no per-byte load latency chain).
__global__ void k_chain(const uint8_t* __restrict__ dec,
                        const uint8_t* __restrict__ Mend,
                        uint8_t* __restrict__ st2) {
  __shared__ uint8_t m[NCHUNK * 9];
  __shared__ uint8_t entry[NCHUNK];
  int b = blockIdx.x;
  for (int idx = threadIdx.x; idx < NCHUNK * 9; idx += blockDim.x)
    m[idx] = Mend[b * NCHUNK * 9 + idx];
  __syncthreads();
  if (threadIdx.x == 0) {
    int sigma = 4;  // (prev2,prev1) = (1,1)
    for (int cc = 0; cc < NCHUNK; ++cc) {
      entry[cc] = (uint8_t)sigma;
      sigma = m[cc * 9 + sigma];
    }
  }
  __syncthreads();
  int c = threadIdx.x;
  int t0 = c * CHUNK;
  int sigma = entry[c];
  const uint32_t* dw = (const uint32_t*)(dec + b * T_LEN + t0);  // 4-aligned
  uint8_t* s2 = st2 + b * T_LEN;
  if (c == 0) s2[0] = 1;  // st[1] = 1 -> st2[0]
#pragma unroll 8
  for (int wi = 0; wi < CHUNK / 4; ++wi) {
    uint32_t word = dw[wi];
#pragma unroll
    for (int r = 0; r < 4; ++r) {
      int t = t0 + 4 * wi + r;
      uint32_t dv = (word >> (8 * r)) & 0xFFu;
      int s = (sigma == 5) ? (int)(dv >> 2) : (int)(dv & 3u);
      if (t < NSTEP) s2[t + 1] = (uint8_t)s;  // guard: don't stomp next batch's st2[0]
      sigma = (sigma % 3) * 3 + s;
    }
  }
}

// -------- Kernel 3: flat-output gather (exact full-line stores) ------------
// out treated as a flat array of 16*256*8190 = 33,546,240 floats
// (= 32760 blocks * 256 threads * 4 floats exactly). Thread g owns flat
// [4g..4g+3]: every store is one 16B-aligned f32x4 nt store; each wave
// writes an exactly-aligned 1KB span, each block 4KB -> ZERO partial cache
// lines on the write stream, no tail threads. (row, j) recovered via
// constant-divisor magic-mul; even rows have j%4==0, odd rows j%4==2, giving
// the two aligned-float4-window select paths (semantics identical to the
// validated row-tiled gather: out[row][j] = x[row][j + st2[b][j]]).
// Row-crossing tiles exist only at even row r, j=8188 (2 outs from r, 2 from
// r+1, same batch since i<=254) -- 2048 of 8.4M threads, still one aligned
// float4 store. Reads: two aligned float4 per thread, 16B lane pitch; the
// second load hits the neighbor lane's line in L1 -> no extra HBM traffic.
// nt stores keep the output stream from thrashing x out of L3.
__global__ void __launch_bounds__(256) k_gather(const float* __restrict__ x,
                                                const uint8_t* __restrict__ st2,
                                                float* __restrict__ out) {
  uint32_t g = blockIdx.x * 256u + threadIdx.x;   // 0..8386559
  uint32_t f = g * 4u;                            // flat out index, %4==0
  uint32_t row = f / 8190u;                       // magic-mul division
  uint32_t j = f - row * 8190u;                   // j%4 == 2*(row&1)
  uint32_t b = row >> 8;
  const float* xr = x + (size_t)row * (size_t)T_LEN;
  const uint8_t* sp = st2 + (size_t)b * (size_t)T_LEN;

  if (j <= 8186u) {                               // tile within one row
    float res[4];
    if ((row & 1u) == 0u) {                       // even row: j%4 == 0
      uint32_t J = j;
      float4 A  = *(const float4*)(xr + J);       // x[J..J+3]
      float4 Bv = *(const float4*)(xr + J + 4);   // x[J+4..J+7]
      uint32_t s0 = *(const uint32_t*)(sp + J);   // st2[J..J+3]
      float w[8] = {A.x, A.y, A.z, A.w, Bv.x, Bv.y, Bv.z, Bv.w};
#pragma unroll
      for (int m = 0; m < 4; ++m) {
        uint32_t s = (s0 >> (8 * m)) & 0xFFu;
        res[m] = (s == 0) ? w[m] : ((s == 1) ? w[m + 1] : w[m + 2]);
      }
    } else {                                      // odd row: j%4 == 2
      uint32_t J = j - 2u;                        // J%4 == 0
      float4 A  = *(const float4*)(xr + J);       // x[J..J+3] = x[j-2..j+1]
      float4 Bv = *(const float4*)(xr + J + 4);   // x[j+2..j+5]
      uint32_t s0 = *(const uint32_t*)(sp + J);   // st2[j-2..j+1]
      uint32_t s1 = *(const uint32_t*)(sp + J + 4); // st2[j+2..j+5]
      float w[8] = {A.x, A.y, A.z, A.w, Bv.x, Bv.y, Bv.z, Bv.w};
      uint32_t sb[4] = { (s0 >> 16) & 0xFFu, s0 >> 24,
                         s1 & 0xFFu, (s1 >> 8) & 0xFFu };  // st2[j..j+3]
#pragma unroll
      for (int m = 0; m < 4; ++m) {
        uint32_t s = sb[m];
        res[m] = (s == 0) ? w[m + 2] : ((s == 1) ? w[m + 3] : w[m + 4]);
      }
    }
    f32x4 r = { res[0], res[1], res[2], res[3] };
    __builtin_nontemporal_store(r, (f32x4*)(out + f));
  } else {
    // row-crossing tile: even row r at j=8188 -> outs r[8188], r[8189],
    // (r+1)[0], (r+1)[1]; r+1 is the same batch (i = row&255 <= 254).
    float4 A  = *(const float4*)(xr + 8188);      // x[r][8188..8191]
    uint32_t s0 = *(const uint32_t*)(sp + 8188);  // st2[8188..8191]
    uint32_t b0 = s0 & 0xFFu, b1 = (s0 >> 8) & 0xFFu;
    float r0 = (b0 == 0) ? A.x : ((b0 == 1) ? A.y : A.z);
    float r1 = (b1 == 0) ? A.y : ((b1 == 1) ? A.z : A.w);
    const float* xr2 = xr + T_LEN;                // row r+1
    float4 A2 = *(const float4*)(xr2);            // x[r+1][0..3]
    uint32_t q0 = *(const uint32_t*)(sp);         // st2[0..3]
    uint32_t c0 = q0 & 0xFFu, c1 = (q0 >> 8) & 0xFFu;
    float r2 = (c0 == 0) ? A2.x : ((c0 == 1) ? A2.y : A2.z);
    float r3 = (c1 == 0) ? A2.y : ((c1 == 1) ? A2.z : A2.w);
    f32x4 r = { r0, r1, r2, r3 };
    __builtin_nontemporal_store(r, (f32x4*)(out + f));
  }
}

extern "C" void kernel_launch(void* const* d_in, const int* in_sizes, int n_in,
                              void* d_out, int out_size, void* d_ws, size_t ws_size,
                              hipStream_t stream) {
  const float* x   = (const float*)d_in[0];   // float32 input
  const int* seedp = (const int*)d_in[1];
  float* out       = (float*)d_out;           // float32 output

  uint8_t* ws    = (uint8_t*)d_ws;
  uint8_t* dec   = ws;                        // 16*8192 = 131072 B
  uint8_t* st2   = dec + NB * T_LEN;          // 131072 B
  uint8_t* Mend  = st2 + NB * T_LEN;          // 16*64*9 = 9216 B

  k_dec_spec<<<dim3(NCHUNK, NB), CHUNK, 0, stream>>>(seedp, dec, Mend);
  k_chain<<<NB, NCHUNK, 0, stream>>>(dec, Mend, st2);
  // flat out: 33,546,240 floats = 32760 blocks * 256 threads * 4 floats
  k_gather<<<dim3(32760), 256, 0, stream>>>(x, st2, out);
}